// Round 10
// baseline (103.996 us; speedup 1.0000x reference)
//
#include <hip/hip_runtime.h>
#include <hip/hip_bf16.h>

#define D 128
#define RPW 2   // rows per wave in spmm

typedef __attribute__((ext_vector_type(8))) short bf16x8;
typedef __attribute__((ext_vector_type(4))) float f32x4;

// float -> bf16 bits, round-to-nearest-even (cold paths)
__device__ __forceinline__ unsigned short f2bf(float f) {
    union { float f; unsigned u; } uf{f};
    unsigned r = uf.u + 0x7fffu + ((uf.u >> 16) & 1u);
    return (unsigned short)(r >> 16);
}
// hot-path pack: v_cvt_pk_bf16_f32 via intrinsic (RNE)
__device__ __forceinline__ unsigned packcv(float a, float b) {
    __hip_bfloat162 h = __float22bfloat162_rn(make_float2(a, b));
    union { __hip_bfloat162 h; unsigned u; } c{h};
    return c.u;
}
__device__ __forceinline__ float bflo(unsigned u) {
    union { unsigned u; float f; } c{u << 16};
    return c.f;
}
__device__ __forceinline__ float bfhi(unsigned u) {
    union { unsigned u; float f; } c{u & 0xffff0000u};
    return c.f;
}
// decode packed (bf15<<17)|col
__device__ __forceinline__ int pc_col(unsigned u) { return (int)(u & 0x1FFFFu); }
__device__ __forceinline__ float pc_val(unsigned u) {
    union { unsigned u; float f; } c{(u >> 1) & 0xFFFF0000u};
    return c.f;
}

// global -> LDS direct DMA, 16B per lane (dest = wave-uniform base + lane*16)
__device__ __forceinline__ void lds_dma16(const float* g, float* l) {
    __builtin_amdgcn_global_load_lds(
        (const __attribute__((address_space(1))) unsigned*)g,
        (__attribute__((address_space(3))) unsigned*)l, 16, 0, 0);
}

#define FMA8(A, vv, u) \
    A[0] = fmaf(vv, bflo(u.x), A[0]); A[1] = fmaf(vv, bfhi(u.x), A[1]); \
    A[2] = fmaf(vv, bflo(u.y), A[2]); A[3] = fmaf(vv, bfhi(u.y), A[3]); \
    A[4] = fmaf(vv, bflo(u.z), A[4]); A[5] = fmaf(vv, bfhi(u.z), A[5]); \
    A[6] = fmaf(vv, bflo(u.w), A[6]); A[7] = fmaf(vv, bfhi(u.w), A[7]);

// ---------------------------------------------------------------------------
// Kernel 0: rowptr from sorted adj_rows (+ gap fill); pack (val,col) -> u32;
//           convert W to bf16.
// ---------------------------------------------------------------------------
__global__ __launch_bounds__(256) void build_rowptr(const int* __restrict__ rows,
                                                    const int* __restrict__ cols,
                                                    const float* __restrict__ vals,
                                                    const float* __restrict__ W,
                                                    unsigned short* __restrict__ wbf,
                                                    unsigned* __restrict__ pc,
                                                    int2* __restrict__ rowptr,
                                                    int e, int n) {
    int i = blockIdx.x * 256 + threadIdx.x;
    if (i < D * D) wbf[i] = f2bf(W[i]);
    if (i >= e) return;

    // pack: vals in [0,1) -> positive bf16 (15 bits), col < 2^17
    pc[i] = ((unsigned)f2bf(vals[i]) << 17) | (unsigned)cols[i];

    int r = rows[i];
    int prev = (i == 0) ? -1 : rows[i - 1];
    int next = (i == e - 1) ? n : rows[i + 1];
    if (prev != r) {
        rowptr[r].x = i;
        for (int q = prev + 1; q < r; ++q) rowptr[q] = make_int2(i, i);   // empty rows
    }
    if (next != r) {
        rowptr[r].y = i + 1;
        if (i == e - 1)
            for (int q = r + 1; q < n; ++q) rowptr[q] = make_int2(e, e); // trailing empties
    }
}

// ---------------------------------------------------------------------------
// Kernel 1: wi = bf16(x @ W^T), MFMA with swapped operands (D = W·x^T).
//   x tile (64KB fp32, contiguous in x) staged via global_load_lds width-16,
//   with inverse-swizzled per-lane SOURCE + swizzled ds_read (both-sides rule):
//   byte swizzle inner ^= (row&7)<<4 -> fragment reads <=2-way conflicts.
//   W fragments direct from global bf16 (32KB, L1-resident).
// ---------------------------------------------------------------------------
__global__ __launch_bounds__(256) void gemm_mfma(const float* __restrict__ x,
                                                 const unsigned short* __restrict__ wbf,
                                                 unsigned short* __restrict__ wi,
                                                 int nrows) {
    __shared__ __align__(16) float Xs[128 * 128];   // 64 KB fp32

    const int tid = threadIdx.x;
    const int lane = tid & 63;
    const int wv = tid >> 6;
    const int row0 = blockIdx.x * 128;

    // stage: 16 iters x (256 threads * 16B) = 64KB. Dest linear; source
    // pre-swizzled per lane (XOR stays inside the 512B row -> coalescing kept).
#pragma unroll
    for (int it = 0; it < 16; ++it) {
        int A = it * 4096 + wv * 1024 + lane * 16;     // dest byte offset
        int row = A >> 9;
        int inner = (A & 511) ^ ((row & 7) << 4);      // inverse swizzle (involution)
        int gr = min(row0 + row, nrows - 1);
        const float* gsrc = x + (size_t)gr * D + (inner >> 2);
        lds_dma16(gsrc, Xs + (it * 4096 + wv * 1024) / 4);
    }
    __syncthreads();

    const int m_base = wv * 32;           // wave's 32 nodes within tile
    const int lrow = lane & 15;
    const int lk8 = (lane >> 4) * 8;

    // B operand: x fragments from swizzled LDS, packed to bf16
    bf16x8 xfrag[2][4];
#pragma unroll
    for (int xb = 0; xb < 2; ++xb)
#pragma unroll
        for (int kb = 0; kb < 4; ++kb) {
            int r = m_base + xb * 16 + lrow;
            int innerB = (kb * 32 + lk8) * 4;          // byte offset within row
            int b0 = r * 512 + ((innerB) ^ ((r & 7) << 4));
            int b1 = r * 512 + ((innerB + 16) ^ ((r & 7) << 4));
            f32x4 f0 = *(const f32x4*)((const char*)Xs + b0);
            f32x4 f1 = *(const f32x4*)((const char*)Xs + b1);
            union { bf16x8 v; unsigned u[4]; } cv;
            cv.u[0] = packcv(f0.x, f0.y);
            cv.u[1] = packcv(f0.z, f0.w);
            cv.u[2] = packcv(f1.x, f1.y);
            cv.u[3] = packcv(f1.z, f1.w);
            xfrag[xb][kb] = cv.v;
        }

    f32x4 acc[2][8];
#pragma unroll
    for (int xb = 0; xb < 2; ++xb)
#pragma unroll
        for (int cb = 0; cb < 8; ++cb)
            acc[xb][cb] = (f32x4){0.f, 0.f, 0.f, 0.f};

#pragma unroll
    for (int cb = 0; cb < 8; ++cb) {
#pragma unroll
        for (int kb = 0; kb < 4; ++kb) {
            // A operand: W row (channel) from global (L1-resident 32KB)
            bf16x8 wfrag = *(const bf16x8*)(wbf + (cb * 16 + lrow) * 128 + kb * 32 + lk8);
            acc[0][cb] = __builtin_amdgcn_mfma_f32_16x16x32_bf16(wfrag, xfrag[0][kb], acc[0][cb], 0, 0, 0);
            acc[1][cb] = __builtin_amdgcn_mfma_f32_16x16x32_bf16(wfrag, xfrag[1][kb], acc[1][cb], 0, 0, 0);
        }
    }

    // D layout: col(lane&15)=node, row((lane>>4)*4+j)=channel
#pragma unroll
    for (int xb = 0; xb < 2; ++xb) {
        int g = row0 + m_base + xb * 16 + lrow;
        if (g < nrows) {
#pragma unroll
            for (int cb = 0; cb < 8; ++cb) {
                uint2 o;
                o.x = packcv(acc[xb][cb][0], acc[xb][cb][1]);
                o.y = packcv(acc[xb][cb][2], acc[xb][cb][3]);
                *(uint2*)(wi + (size_t)g * D + cb * 16 + (lane >> 4) * 4) = o;
            }
        }
    }
}

// ---------------------------------------------------------------------------
// Kernel 2: out[r] = relu(bias + sum vals[e]*wi[cols[e]])  (wi bf16, pc packed)
//   2 rows/wave; per row both 16-edge quads issued together -> 8 uint4
//   gathers in flight. (r8 structure — best measured; nt hints reverted.)
// ---------------------------------------------------------------------------
__global__ __launch_bounds__(256) void spmm_relu(const unsigned short* __restrict__ wi,
                                                 const int2* __restrict__ rowptr,
                                                 const unsigned* __restrict__ pc,
                                                 const float* __restrict__ bias,
                                                 float* __restrict__ out,
                                                 int n) {
    const int lane = threadIdx.x & 63;
    const int R0 = (blockIdx.x * 4 + (threadIdx.x >> 6)) * RPW;
    if (R0 >= n) return;
    const int nr = min(RPW, n - R0);

    const int2 rp = rowptr[R0 + min(lane, nr - 1)];
    const int ch = (lane & 15) * 8;   // channel base this lane gathers
    const int sub = lane >> 4;        // lane's slot within each quad

    float4 b0 = *(const float4*)(bias + (lane & 15) * 8);
    float4 b1 = *(const float4*)(bias + (lane & 15) * 8 + 4);

    // prologue: stage row 0's first chunk (coalesced)
    int st = __shfl(rp.x, 0), en = __shfl(rp.y, 0);
    unsigned u = 0;
    { int idx = st + lane; if (idx < en) u = pc[idx]; }

    for (int j = 0; j < nr; ++j) {
        // prefetch next row's metadata
        int st_n = 0, en_n = 0; unsigned u_n = 0;
        if (j + 1 < nr) {
            st_n = __shfl(rp.x, j + 1); en_n = __shfl(rp.y, j + 1);
            int idx = st_n + lane; if (idx < en_n) u_n = pc[idx];
        }

        float a0[8] = {0.f, 0.f, 0.f, 0.f, 0.f, 0.f, 0.f, 0.f};
        float a1[8] = {0.f, 0.f, 0.f, 0.f, 0.f, 0.f, 0.f, 0.f};

        const int cnt = min(en - st, 64);
        if (cnt > 0) {
            // edges [0,32): both quads issued together -> 8 gathers in flight.
            unsigned mA[4], mB[4];
#pragma unroll
            for (int p = 0; p < 4; ++p) {
                mA[p] = __shfl(u, sub + 4 * p);
                mB[p] = __shfl(u, 16 + sub + 4 * p);
            }
            uint4 uA[4], uB[4];
#pragma unroll
            for (int p = 0; p < 4; ++p) uA[p] = *(const uint4*)(wi + (size_t)pc_col(mA[p]) * D + ch);
#pragma unroll
            for (int p = 0; p < 4; ++p) uB[p] = *(const uint4*)(wi + (size_t)pc_col(mB[p]) * D + ch);
#pragma unroll
            for (int p = 0; p < 4; ++p) {
                FMA8(a0, pc_val(mA[p]), uA[p]);
                FMA8(a1, pc_val(mB[p]), uB[p]);
            }
            // edges [32, cnt): rows with >32 edges
            for (int E = 32; E < cnt; E += 16) {
#pragma unroll
                for (int p = 0; p < 4; ++p) {
                    unsigned m = __shfl(u, E + sub + 4 * p);
                    uint4 uq = *(const uint4*)(wi + (size_t)pc_col(m) * D + ch);
                    FMA8(a0, pc_val(m), uq);
                }
            }
        }
        // very rare rows with >64 edges
        for (int base = st + 64; base < en; base += 64) {
            unsigned uu = 0;
            { int idx = base + lane; if (idx < en) uu = pc[idx]; }
            const int cnt2 = min(en - base, 64);
            for (int E = 0; E < cnt2; E += 16) {
#pragma unroll
                for (int p = 0; p < 4; ++p) {
                    unsigned m = __shfl(uu, E + sub + 4 * p);
                    uint4 uq = *(const uint4*)(wi + (size_t)pc_col(m) * D + ch);
                    FMA8(a1, pc_val(m), uq);
                }
            }
        }

        // reduce across the 4 sub-groups + store
        float r8[8];
#pragma unroll
        for (int t = 0; t < 8; ++t) {
            float s = a0[t] + a1[t];
            s += __shfl_xor(s, 16);
            s += __shfl_xor(s, 32);
            r8[t] = s;
        }
        if (lane < 16) {
            float4 o0, o1;
            o0.x = fmaxf(r8[0] + b0.x, 0.f);
            o0.y = fmaxf(r8[1] + b0.y, 0.f);
            o0.z = fmaxf(r8[2] + b0.z, 0.f);
            o0.w = fmaxf(r8[3] + b0.w, 0.f);
            o1.x = fmaxf(r8[4] + b1.x, 0.f);
            o1.y = fmaxf(r8[5] + b1.y, 0.f);
            o1.z = fmaxf(r8[6] + b1.z, 0.f);
            o1.w = fmaxf(r8[7] + b1.w, 0.f);
            *(float4*)(out + (size_t)(R0 + j) * D + lane * 8) = o0;
            *(float4*)(out + (size_t)(R0 + j) * D + lane * 8 + 4) = o1;
        }

        st = st_n; en = en_n; u = u_n;
    }
}

// ---------------------------------------------------------------------------
extern "C" void kernel_launch(void* const* d_in, const int* in_sizes, int n_in,
                              void* d_out, int out_size, void* d_ws, size_t ws_size,
                              hipStream_t stream) {
    const float* x        = (const float*)d_in[0];
    const int*   adj_rows = (const int*)d_in[1];
    const int*   adj_cols = (const int*)d_in[2];
    const float* adj_vals = (const float*)d_in[3];
    const float* weight   = (const float*)d_in[4];
    const float* bias     = (const float*)d_in[5];
    float*       out      = (float*)d_out;

    const int n = in_sizes[0] / D;   // 100000
    const int e = in_sizes[1];       // 1600000

    // workspace layout
    unsigned short* wi = (unsigned short*)d_ws;                 // n*128 bf16 = 25.6 MB
    size_t off = ((size_t)n * D * sizeof(unsigned short) + 255) & ~(size_t)255;
    int2* rowptr = (int2*)((char*)d_ws + off);                  // n int2 = 0.8 MB
    unsigned* pc = (unsigned*)(rowptr + n);                     // e u32 = 6.4 MB
    unsigned short* wbf = (unsigned short*)(pc + e);            // 32 KB bf16 W

    build_rowptr<<<(e + 255) / 256, 256, 0, stream>>>(adj_rows, adj_cols, adj_vals,
                                                      weight, wbf, pc, rowptr, e, n);

    gemm_mfma<<<(n + 127) / 128, 256, 0, stream>>>(x, wbf, wi, n);

    spmm_relu<<<(n + 4 * RPW - 1) / (4 * RPW), 256, 0, stream>>>(
        wi, rowptr, pc, bias, out, n);
}

// Round 11
// 93.956 us; speedup vs baseline: 1.1069x; 1.1069x over previous
//
#include <hip/hip_runtime.h>
#include <hip/hip_bf16.h>

#define D 128
#define RPW 2   // rows per wave in spmm

typedef __attribute__((ext_vector_type(8))) short bf16x8;
typedef __attribute__((ext_vector_type(4))) float f32x4;

// float -> bf16 bits, round-to-nearest-even (cold paths)
__device__ __forceinline__ unsigned short f2bf(float f) {
    union { float f; unsigned u; } uf{f};
    unsigned r = uf.u + 0x7fffu + ((uf.u >> 16) & 1u);
    return (unsigned short)(r >> 16);
}
// hot-path pack: v_cvt_pk_bf16_f32 via intrinsic (RNE)
__device__ __forceinline__ unsigned packcv(float a, float b) {
    __hip_bfloat162 h = __float22bfloat162_rn(make_float2(a, b));
    union { __hip_bfloat162 h; unsigned u; } c{h};
    return c.u;
}
__device__ __forceinline__ float bflo(unsigned u) {
    union { unsigned u; float f; } c{u << 16};
    return c.f;
}
__device__ __forceinline__ float bfhi(unsigned u) {
    union { unsigned u; float f; } c{u & 0xffff0000u};
    return c.f;
}
// decode packed (bf15<<17)|col
__device__ __forceinline__ int pc_col(unsigned u) { return (int)(u & 0x1FFFFu); }
__device__ __forceinline__ float pc_val(unsigned u) {
    union { unsigned u; float f; } c{(u >> 1) & 0xFFFF0000u};
    return c.f;
}

#define FMA8(A, vv, u) \
    A[0] = fmaf(vv, bflo(u.x), A[0]); A[1] = fmaf(vv, bfhi(u.x), A[1]); \
    A[2] = fmaf(vv, bflo(u.y), A[2]); A[3] = fmaf(vv, bfhi(u.y), A[3]); \
    A[4] = fmaf(vv, bflo(u.z), A[4]); A[5] = fmaf(vv, bfhi(u.z), A[5]); \
    A[6] = fmaf(vv, bflo(u.w), A[6]); A[7] = fmaf(vv, bfhi(u.w), A[7]);

// ---------------------------------------------------------------------------
// Kernel 0: rowptr from sorted adj_rows (+ gap fill); pack (val,col) -> u32;
//           convert W to bf16.
// ---------------------------------------------------------------------------
__global__ __launch_bounds__(256) void build_rowptr(const int* __restrict__ rows,
                                                    const int* __restrict__ cols,
                                                    const float* __restrict__ vals,
                                                    const float* __restrict__ W,
                                                    unsigned short* __restrict__ wbf,
                                                    unsigned* __restrict__ pc,
                                                    int2* __restrict__ rowptr,
                                                    int e, int n) {
    int i = blockIdx.x * 256 + threadIdx.x;
    if (i < D * D) wbf[i] = f2bf(W[i]);
    if (i >= e) return;

    // pack: vals in [0,1) -> positive bf16 (15 bits), col < 2^17
    pc[i] = ((unsigned)f2bf(vals[i]) << 17) | (unsigned)cols[i];

    int r = rows[i];
    int prev = (i == 0) ? -1 : rows[i - 1];
    int next = (i == e - 1) ? n : rows[i + 1];
    if (prev != r) {
        rowptr[r].x = i;
        for (int q = prev + 1; q < r; ++q) rowptr[q] = make_int2(i, i);   // empty rows
    }
    if (next != r) {
        rowptr[r].y = i + 1;
        if (i == e - 1)
            for (int q = r + 1; q < n; ++q) rowptr[q] = make_int2(e, e); // trailing empties
    }
}

// ---------------------------------------------------------------------------
// Kernel 1: wi = bf16(x @ W^T), MFMA with swapped operands (D = W·x^T).
//   W staged once into swizzled LDS (32 KB); x fragments loaded per-lane
//   directly from global fp32 inside the fragment loop (r7 config — best
//   measured; hoisting the loads into regs costs +64 VGPRs and regresses).
// ---------------------------------------------------------------------------
__global__ __launch_bounds__(256) void gemm_mfma(const float* __restrict__ x,
                                                 const unsigned short* __restrict__ wbf,
                                                 unsigned short* __restrict__ wi,
                                                 int nrows) {
    __shared__ __align__(16) unsigned short Ws[128 * 128];   // 32 KB, swizzled

    const int tid = threadIdx.x;
    // stage W (already bf16): 16384 elems / 256 threads = 8 bf16 x 8 iters
#pragma unroll
    for (int it = 0; it < 8; ++it) {
        int elem = it * 2048 + tid * 8;
        int r = elem >> 7, k = elem & 127;
        int idx = (r * 128 + k) ^ ((r & 7) << 3);    // stays 8-elem aligned
        *(uint4*)&Ws[idx] = *(const uint4*)(wbf + elem);
    }
    __syncthreads();

    const int lane = tid & 63;
    const int row0 = blockIdx.x * 128 + (tid >> 6) * 32;  // wave's 32 nodes
    const int lrow = lane & 15;
    const int lk8 = (lane >> 4) * 8;

    // B operand: x fragments direct from global, cvt_pk packed
    bf16x8 xfrag[2][4];
#pragma unroll
    for (int xb = 0; xb < 2; ++xb)
#pragma unroll
        for (int kb = 0; kb < 4; ++kb) {
            int gr = min(row0 + xb * 16 + lrow, nrows - 1);
            const float4* p = (const float4*)(x + (size_t)gr * D + kb * 32 + lk8);
            float4 f0 = p[0], f1 = p[1];
            union { bf16x8 v; unsigned u[4]; } cv;
            cv.u[0] = packcv(f0.x, f0.y);
            cv.u[1] = packcv(f0.z, f0.w);
            cv.u[2] = packcv(f1.x, f1.y);
            cv.u[3] = packcv(f1.z, f1.w);
            xfrag[xb][kb] = cv.v;
        }

    f32x4 acc[2][8];
#pragma unroll
    for (int xb = 0; xb < 2; ++xb)
#pragma unroll
        for (int cb = 0; cb < 8; ++cb)
            acc[xb][cb] = (f32x4){0.f, 0.f, 0.f, 0.f};

#pragma unroll
    for (int cb = 0; cb < 8; ++cb) {
#pragma unroll
        for (int kb = 0; kb < 4; ++kb) {
            int wrow = cb * 16 + lrow;
            int idx = (wrow * 128 + kb * 32 + lk8) ^ ((wrow & 7) << 3);
            bf16x8 wfrag = *(const bf16x8*)&Ws[idx];
            acc[0][cb] = __builtin_amdgcn_mfma_f32_16x16x32_bf16(wfrag, xfrag[0][kb], acc[0][cb], 0, 0, 0);
            acc[1][cb] = __builtin_amdgcn_mfma_f32_16x16x32_bf16(wfrag, xfrag[1][kb], acc[1][cb], 0, 0, 0);
        }
    }

    // D layout: col(lane&15)=node, row((lane>>4)*4+j)=channel
#pragma unroll
    for (int xb = 0; xb < 2; ++xb) {
        int g = row0 + xb * 16 + lrow;
        if (g < nrows) {
#pragma unroll
            for (int cb = 0; cb < 8; ++cb) {
                uint2 o;
                o.x = packcv(acc[xb][cb][0], acc[xb][cb][1]);
                o.y = packcv(acc[xb][cb][2], acc[xb][cb][3]);
                *(uint2*)(wi + (size_t)g * D + cb * 16 + (lane >> 4) * 4) = o;
            }
        }
    }
}

// ---------------------------------------------------------------------------
// Kernel 2: out[r] = relu(bias + sum vals[e]*wi[cols[e]])  (wi bf16, pc packed)
//   2 rows/wave; per row both 16-edge quads issued together -> 8 uint4
//   gathers in flight. (r8 structure verbatim — best measured: 63.6 us.)
// ---------------------------------------------------------------------------
__global__ __launch_bounds__(256) void spmm_relu(const unsigned short* __restrict__ wi,
                                                 const int2* __restrict__ rowptr,
                                                 const unsigned* __restrict__ pc,
                                                 const float* __restrict__ bias,
                                                 float* __restrict__ out,
                                                 int n) {
    const int lane = threadIdx.x & 63;
    const int R0 = (blockIdx.x * 4 + (threadIdx.x >> 6)) * RPW;
    if (R0 >= n) return;
    const int nr = min(RPW, n - R0);

    const int2 rp = rowptr[R0 + min(lane, nr - 1)];
    const int ch = (lane & 15) * 8;   // channel base this lane gathers
    const int sub = lane >> 4;        // lane's slot within each quad

    float4 b0 = *(const float4*)(bias + (lane & 15) * 8);
    float4 b1 = *(const float4*)(bias + (lane & 15) * 8 + 4);

    // prologue: stage row 0's first chunk (coalesced)
    int st = __shfl(rp.x, 0), en = __shfl(rp.y, 0);
    unsigned u = 0;
    { int idx = st + lane; if (idx < en) u = pc[idx]; }

    for (int j = 0; j < nr; ++j) {
        // prefetch next row's metadata
        int st_n = 0, en_n = 0; unsigned u_n = 0;
        if (j + 1 < nr) {
            st_n = __shfl(rp.x, j + 1); en_n = __shfl(rp.y, j + 1);
            int idx = st_n + lane; if (idx < en_n) u_n = pc[idx];
        }

        float a0[8] = {0.f, 0.f, 0.f, 0.f, 0.f, 0.f, 0.f, 0.f};
        float a1[8] = {0.f, 0.f, 0.f, 0.f, 0.f, 0.f, 0.f, 0.f};

        const int cnt = min(en - st, 64);
        if (cnt > 0) {
            // edges [0,32): both quads issued together -> 8 gathers in flight.
            unsigned mA[4], mB[4];
#pragma unroll
            for (int p = 0; p < 4; ++p) {
                mA[p] = __shfl(u, sub + 4 * p);
                mB[p] = __shfl(u, 16 + sub + 4 * p);
            }
            uint4 uA[4], uB[4];
#pragma unroll
            for (int p = 0; p < 4; ++p) uA[p] = *(const uint4*)(wi + (size_t)pc_col(mA[p]) * D + ch);
#pragma unroll
            for (int p = 0; p < 4; ++p) uB[p] = *(const uint4*)(wi + (size_t)pc_col(mB[p]) * D + ch);
#pragma unroll
            for (int p = 0; p < 4; ++p) {
                FMA8(a0, pc_val(mA[p]), uA[p]);
                FMA8(a1, pc_val(mB[p]), uB[p]);
            }
            // edges [32, cnt): rows with >32 edges
            for (int E = 32; E < cnt; E += 16) {
#pragma unroll
                for (int p = 0; p < 4; ++p) {
                    unsigned m = __shfl(u, E + sub + 4 * p);
                    uint4 uq = *(const uint4*)(wi + (size_t)pc_col(m) * D + ch);
                    FMA8(a0, pc_val(m), uq);
                }
            }
        }
        // very rare rows with >64 edges
        for (int base = st + 64; base < en; base += 64) {
            unsigned uu = 0;
            { int idx = base + lane; if (idx < en) uu = pc[idx]; }
            const int cnt2 = min(en - base, 64);
            for (int E = 0; E < cnt2; E += 16) {
#pragma unroll
                for (int p = 0; p < 4; ++p) {
                    unsigned m = __shfl(uu, E + sub + 4 * p);
                    uint4 uq = *(const uint4*)(wi + (size_t)pc_col(m) * D + ch);
                    FMA8(a1, pc_val(m), uq);
                }
            }
        }

        // reduce across the 4 sub-groups + store
        float r8[8];
#pragma unroll
        for (int t = 0; t < 8; ++t) {
            float s = a0[t] + a1[t];
            s += __shfl_xor(s, 16);
            s += __shfl_xor(s, 32);
            r8[t] = s;
        }
        if (lane < 16) {
            float4 o0, o1;
            o0.x = fmaxf(r8[0] + b0.x, 0.f);
            o0.y = fmaxf(r8[1] + b0.y, 0.f);
            o0.z = fmaxf(r8[2] + b0.z, 0.f);
            o0.w = fmaxf(r8[3] + b0.w, 0.f);
            o1.x = fmaxf(r8[4] + b1.x, 0.f);
            o1.y = fmaxf(r8[5] + b1.y, 0.f);
            o1.z = fmaxf(r8[6] + b1.z, 0.f);
            o1.w = fmaxf(r8[7] + b1.w, 0.f);
            *(float4*)(out + (size_t)(R0 + j) * D + lane * 8) = o0;
            *(float4*)(out + (size_t)(R0 + j) * D + lane * 8 + 4) = o1;
        }

        st = st_n; en = en_n; u = u_n;
    }
}

// ---------------------------------------------------------------------------
extern "C" void kernel_launch(void* const* d_in, const int* in_sizes, int n_in,
                              void* d_out, int out_size, void* d_ws, size_t ws_size,
                              hipStream_t stream) {
    const float* x        = (const float*)d_in[0];
    const int*   adj_rows = (const int*)d_in[1];
    const int*   adj_cols = (const int*)d_in[2];
    const float* adj_vals = (const float*)d_in[3];
    const float* weight   = (const float*)d_in[4];
    const float* bias     = (const float*)d_in[5];
    float*       out      = (float*)d_out;

    const int n = in_sizes[0] / D;   // 100000
    const int e = in_sizes[1];       // 1600000

    // workspace layout
    unsigned short* wi = (unsigned short*)d_ws;                 // n*128 bf16 = 25.6 MB
    size_t off = ((size_t)n * D * sizeof(unsigned short) + 255) & ~(size_t)255;
    int2* rowptr = (int2*)((char*)d_ws + off);                  // n int2 = 0.8 MB
    unsigned* pc = (unsigned*)(rowptr + n);                     // e u32 = 6.4 MB
    unsigned short* wbf = (unsigned short*)(pc + e);            // 32 KB bf16 W

    build_rowptr<<<(e + 255) / 256, 256, 0, stream>>>(adj_rows, adj_cols, adj_vals,
                                                      weight, wbf, pc, rowptr, e, n);

    gemm_mfma<<<(n + 127) / 128, 256, 0, stream>>>(x, wbf, wi, n);

    spmm_relu<<<(n + 4 * RPW - 1) / (4 * RPW), 256, 0, stream>>>(
        wi, rowptr, pc, bias, out, n);
}

// Round 12
// 89.437 us; speedup vs baseline: 1.1628x; 1.0505x over previous
//
#include <hip/hip_runtime.h>
#include <hip/hip_bf16.h>

#define D 128
#define RPW 2   // rows per wave in spmm

typedef __attribute__((ext_vector_type(8))) short bf16x8;
typedef __attribute__((ext_vector_type(4))) float f32x4;

// float -> bf16 bits, round-to-nearest-even (cold paths)
__device__ __forceinline__ unsigned short f2bf(float f) {
    union { float f; unsigned u; } uf{f};
    unsigned r = uf.u + 0x7fffu + ((uf.u >> 16) & 1u);
    return (unsigned short)(r >> 16);
}
// hot-path pack: v_cvt_pk_bf16_f32 via intrinsic (RNE)
__device__ __forceinline__ unsigned packcv(float a, float b) {
    __hip_bfloat162 h = __float22bfloat162_rn(make_float2(a, b));
    union { __hip_bfloat162 h; unsigned u; } c{h};
    return c.u;
}
__device__ __forceinline__ float bflo(unsigned u) {
    union { unsigned u; float f; } c{u << 16};
    return c.f;
}
__device__ __forceinline__ float bfhi(unsigned u) {
    union { unsigned u; float f; } c{u & 0xffff0000u};
    return c.f;
}
// decode packed (bf15<<17)|col
__device__ __forceinline__ int pc_col(unsigned u) { return (int)(u & 0x1FFFFu); }
__device__ __forceinline__ float pc_val(unsigned u) {
    union { unsigned u; float f; } c{(u >> 1) & 0xFFFF0000u};
    return c.f;
}

#define FMA8(A, vv, u) \
    A[0] = fmaf(vv, bflo(u.x), A[0]); A[1] = fmaf(vv, bfhi(u.x), A[1]); \
    A[2] = fmaf(vv, bflo(u.y), A[2]); A[3] = fmaf(vv, bfhi(u.y), A[3]); \
    A[4] = fmaf(vv, bflo(u.z), A[4]); A[5] = fmaf(vv, bfhi(u.z), A[5]); \
    A[6] = fmaf(vv, bflo(u.w), A[6]); A[7] = fmaf(vv, bfhi(u.w), A[7]);

// ---------------------------------------------------------------------------
// Kernel 1 (fused): blocks [0, gemm_blocks) do the MFMA GEMM; blocks
// [gemm_blocks, ...) build rowptr + pack (val,col). The two halves are
// data-independent, so they share one dispatch and overlap on the CUs.
//   GEMM: wi = bf16(x @ W^T), swapped-operand MFMA (D = W·x^T). W converted
//   fp32->bf16 during the per-block LDS stage (64KB L2-hot read per block).
// ---------------------------------------------------------------------------
__global__ __launch_bounds__(256) void gemm_and_rowptr(
        const float* __restrict__ x,
        const float* __restrict__ W,
        const int* __restrict__ rows,
        const int* __restrict__ cols,
        const float* __restrict__ vals,
        unsigned short* __restrict__ wi,
        unsigned* __restrict__ pc,
        int2* __restrict__ rowptr,
        int nrows, int e, int gemm_blocks) {
    const int tid = threadIdx.x;

    if (blockIdx.x >= gemm_blocks) {
        // ---------------- rowptr + pack half ----------------
        int i = (blockIdx.x - gemm_blocks) * 256 + tid;
        if (i >= e) return;

        // pack: vals in [0,1) -> positive bf16 (15 bits), col < 2^17
        pc[i] = ((unsigned)f2bf(vals[i]) << 17) | (unsigned)cols[i];

        int r = rows[i];
        int prev = (i == 0) ? -1 : rows[i - 1];
        int next = (i == e - 1) ? nrows : rows[i + 1];
        if (prev != r) {
            rowptr[r].x = i;
            for (int q = prev + 1; q < r; ++q) rowptr[q] = make_int2(i, i);
        }
        if (next != r) {
            rowptr[r].y = i + 1;
            if (i == e - 1)
                for (int q = r + 1; q < nrows; ++q) rowptr[q] = make_int2(e, e);
        }
        return;
    }

    // ---------------- GEMM half ----------------
    __shared__ __align__(16) unsigned short Ws[128 * 128];   // 32 KB, swizzled

    // stage W with fp32->bf16 conversion: 16384 elems / 256 threads, 8 iters
#pragma unroll
    for (int it = 0; it < 8; ++it) {
        int elem = it * 2048 + tid * 8;
        int r = elem >> 7, k = elem & 127;
        int idx = (r * 128 + k) ^ ((r & 7) << 3);    // stays 8-elem aligned
        const float4* wp = (const float4*)(W + elem);
        float4 w0 = wp[0], w1 = wp[1];
        uint4 o;
        o.x = packcv(w0.x, w0.y);
        o.y = packcv(w0.z, w0.w);
        o.z = packcv(w1.x, w1.y);
        o.w = packcv(w1.z, w1.w);
        *(uint4*)&Ws[idx] = o;
    }
    __syncthreads();

    const int lane = tid & 63;
    const int row0 = blockIdx.x * 128 + (tid >> 6) * 32;  // wave's 32 nodes
    const int lrow = lane & 15;
    const int lk8 = (lane >> 4) * 8;

    // B operand: x fragments direct from global, cvt_pk packed
    bf16x8 xfrag[2][4];
#pragma unroll
    for (int xb = 0; xb < 2; ++xb)
#pragma unroll
        for (int kb = 0; kb < 4; ++kb) {
            int gr = min(row0 + xb * 16 + lrow, nrows - 1);
            const float4* p = (const float4*)(x + (size_t)gr * D + kb * 32 + lk8);
            float4 f0 = p[0], f1 = p[1];
            union { bf16x8 v; unsigned u[4]; } cv;
            cv.u[0] = packcv(f0.x, f0.y);
            cv.u[1] = packcv(f0.z, f0.w);
            cv.u[2] = packcv(f1.x, f1.y);
            cv.u[3] = packcv(f1.z, f1.w);
            xfrag[xb][kb] = cv.v;
        }

    f32x4 acc[2][8];
#pragma unroll
    for (int xb = 0; xb < 2; ++xb)
#pragma unroll
        for (int cb = 0; cb < 8; ++cb)
            acc[xb][cb] = (f32x4){0.f, 0.f, 0.f, 0.f};

#pragma unroll
    for (int cb = 0; cb < 8; ++cb) {
#pragma unroll
        for (int kb = 0; kb < 4; ++kb) {
            int wrow = cb * 16 + lrow;
            int idx = (wrow * 128 + kb * 32 + lk8) ^ ((wrow & 7) << 3);
            bf16x8 wfrag = *(const bf16x8*)&Ws[idx];
            acc[0][cb] = __builtin_amdgcn_mfma_f32_16x16x32_bf16(wfrag, xfrag[0][kb], acc[0][cb], 0, 0, 0);
            acc[1][cb] = __builtin_amdgcn_mfma_f32_16x16x32_bf16(wfrag, xfrag[1][kb], acc[1][cb], 0, 0, 0);
        }
    }

    // D layout: col(lane&15)=node, row((lane>>4)*4+j)=channel
#pragma unroll
    for (int xb = 0; xb < 2; ++xb) {
        int g = row0 + xb * 16 + lrow;
        if (g < nrows) {
#pragma unroll
            for (int cb = 0; cb < 8; ++cb) {
                uint2 o;
                o.x = packcv(acc[xb][cb][0], acc[xb][cb][1]);
                o.y = packcv(acc[xb][cb][2], acc[xb][cb][3]);
                *(uint2*)(wi + (size_t)g * D + cb * 16 + (lane >> 4) * 4) = o;
            }
        }
    }
}

// ---------------------------------------------------------------------------
// Kernel 2: out[r] = relu(bias + sum vals[e]*wi[cols[e]])  (wi bf16, pc packed)
//   2 rows/wave; per row both 16-edge quads issued together -> 8 uint4
//   gathers in flight. (r8 structure verbatim — best measured: 63.6 us.)
// ---------------------------------------------------------------------------
__global__ __launch_bounds__(256) void spmm_relu(const unsigned short* __restrict__ wi,
                                                 const int2* __restrict__ rowptr,
                                                 const unsigned* __restrict__ pc,
                                                 const float* __restrict__ bias,
                                                 float* __restrict__ out,
                                                 int n) {
    const int lane = threadIdx.x & 63;
    const int R0 = (blockIdx.x * 4 + (threadIdx.x >> 6)) * RPW;
    if (R0 >= n) return;
    const int nr = min(RPW, n - R0);

    const int2 rp = rowptr[R0 + min(lane, nr - 1)];
    const int ch = (lane & 15) * 8;   // channel base this lane gathers
    const int sub = lane >> 4;        // lane's slot within each quad

    float4 b0 = *(const float4*)(bias + (lane & 15) * 8);
    float4 b1 = *(const float4*)(bias + (lane & 15) * 8 + 4);

    // prologue: stage row 0's first chunk (coalesced)
    int st = __shfl(rp.x, 0), en = __shfl(rp.y, 0);
    unsigned u = 0;
    { int idx = st + lane; if (idx < en) u = pc[idx]; }

    for (int j = 0; j < nr; ++j) {
        // prefetch next row's metadata
        int st_n = 0, en_n = 0; unsigned u_n = 0;
        if (j + 1 < nr) {
            st_n = __shfl(rp.x, j + 1); en_n = __shfl(rp.y, j + 1);
            int idx = st_n + lane; if (idx < en_n) u_n = pc[idx];
        }

        float a0[8] = {0.f, 0.f, 0.f, 0.f, 0.f, 0.f, 0.f, 0.f};
        float a1[8] = {0.f, 0.f, 0.f, 0.f, 0.f, 0.f, 0.f, 0.f};

        const int cnt = min(en - st, 64);
        if (cnt > 0) {
            // edges [0,32): both quads issued together -> 8 gathers in flight.
            unsigned mA[4], mB[4];
#pragma unroll
            for (int p = 0; p < 4; ++p) {
                mA[p] = __shfl(u, sub + 4 * p);
                mB[p] = __shfl(u, 16 + sub + 4 * p);
            }
            uint4 uA[4], uB[4];
#pragma unroll
            for (int p = 0; p < 4; ++p) uA[p] = *(const uint4*)(wi + (size_t)pc_col(mA[p]) * D + ch);
#pragma unroll
            for (int p = 0; p < 4; ++p) uB[p] = *(const uint4*)(wi + (size_t)pc_col(mB[p]) * D + ch);
#pragma unroll
            for (int p = 0; p < 4; ++p) {
                FMA8(a0, pc_val(mA[p]), uA[p]);
                FMA8(a1, pc_val(mB[p]), uB[p]);
            }
            // edges [32, cnt): rows with >32 edges
            for (int E = 32; E < cnt; E += 16) {
#pragma unroll
                for (int p = 0; p < 4; ++p) {
                    unsigned m = __shfl(u, E + sub + 4 * p);
                    uint4 uq = *(const uint4*)(wi + (size_t)pc_col(m) * D + ch);
                    FMA8(a0, pc_val(m), uq);
                }
            }
        }
        // very rare rows with >64 edges
        for (int base = st + 64; base < en; base += 64) {
            unsigned uu = 0;
            { int idx = base + lane; if (idx < en) uu = pc[idx]; }
            const int cnt2 = min(en - base, 64);
            for (int E = 0; E < cnt2; E += 16) {
#pragma unroll
                for (int p = 0; p < 4; ++p) {
                    unsigned m = __shfl(uu, E + sub + 4 * p);
                    uint4 uq = *(const uint4*)(wi + (size_t)pc_col(m) * D + ch);
                    FMA8(a1, pc_val(m), uq);
                }
            }
        }

        // reduce across the 4 sub-groups + store
        float r8[8];
#pragma unroll
        for (int t = 0; t < 8; ++t) {
            float s = a0[t] + a1[t];
            s += __shfl_xor(s, 16);
            s += __shfl_xor(s, 32);
            r8[t] = s;
        }
        if (lane < 16) {
            float4 o0, o1;
            o0.x = fmaxf(r8[0] + b0.x, 0.f);
            o0.y = fmaxf(r8[1] + b0.y, 0.f);
            o0.z = fmaxf(r8[2] + b0.z, 0.f);
            o0.w = fmaxf(r8[3] + b0.w, 0.f);
            o1.x = fmaxf(r8[4] + b1.x, 0.f);
            o1.y = fmaxf(r8[5] + b1.y, 0.f);
            o1.z = fmaxf(r8[6] + b1.z, 0.f);
            o1.w = fmaxf(r8[7] + b1.w, 0.f);
            *(float4*)(out + (size_t)(R0 + j) * D + lane * 8) = o0;
            *(float4*)(out + (size_t)(R0 + j) * D + lane * 8 + 4) = o1;
        }

        st = st_n; en = en_n; u = u_n;
    }
}

// ---------------------------------------------------------------------------
extern "C" void kernel_launch(void* const* d_in, const int* in_sizes, int n_in,
                              void* d_out, int out_size, void* d_ws, size_t ws_size,
                              hipStream_t stream) {
    const float* x        = (const float*)d_in[0];
    const int*   adj_rows = (const int*)d_in[1];
    const int*   adj_cols = (const int*)d_in[2];
    const float* adj_vals = (const float*)d_in[3];
    const float* weight   = (const float*)d_in[4];
    const float* bias     = (const float*)d_in[5];
    float*       out      = (float*)d_out;

    const int n = in_sizes[0] / D;   // 100000
    const int e = in_sizes[1];       // 1600000

    // workspace layout
    unsigned short* wi = (unsigned short*)d_ws;                 // n*128 bf16 = 25.6 MB
    size_t off = ((size_t)n * D * sizeof(unsigned short) + 255) & ~(size_t)255;
    int2* rowptr = (int2*)((char*)d_ws + off);                  // n int2 = 0.8 MB
    unsigned* pc = (unsigned*)(rowptr + n);                     // e u32 = 6.4 MB

    const int gemm_blocks = (n + 127) / 128;        // 782
    const int rp_blocks   = (e + 255) / 256;        // 6250

    gemm_and_rowptr<<<gemm_blocks + rp_blocks, 256, 0, stream>>>(
        x, weight, adj_rows, adj_cols, adj_vals, wi, pc, rowptr,
        n, e, gemm_blocks);

    spmm_relu<<<(n + 4 * RPW - 1) / (4 * RPW), 256, 0, stream>>>(
        wi, rowptr, pc, bias, out, n);
}